// Round 4
// baseline (338.039 us; speedup 1.0000x reference)
//
#include <hip/hip_runtime.h>
#include <hip/hip_bf16.h>

#define N_NODES 50000
#define N_EDGES 800000
#define TOT_E   (N_EDGES + N_NODES)
#define NBUCK   ((N_NODES + 127) / 128)     // 391 buckets of 128 dst nodes
#define BCAP    3072                         // bucket capacity (avg 2048, max ~2300)
#define PART_BLOCKS 256
#define EPB     (N_EDGES / PART_BLOCKS)      // 3125 edges per partition block
#define NSHADOW 16                           // shadow copies for fused-stats atomics

typedef __attribute__((ext_vector_type(8))) short short8;
typedef __attribute__((ext_vector_type(4))) float f32x4;

__device__ __forceinline__ unsigned short f2bf(float f) {
  union { float f; unsigned int u; } x; x.f = f;
  unsigned int u = x.u;
  unsigned int r = (u + 0x7FFFu + ((u >> 16) & 1u)) >> 16;  // RNE
  return (unsigned short)r;
}
__device__ __forceinline__ float bflo(unsigned int v) {   // bf16 in low half
  union { unsigned int u; float f; } x; x.u = v << 16; return x.f;
}
__device__ __forceinline__ float bfhi(unsigned int v) {   // bf16 in high half
  union { unsigned int u; float f; } x; x.u = v & 0xffff0000u; return x.f;
}

// ---- init: zero sums/cursors, detect dtype, pre-convert W -> bf16 --------
// Grid = 64 blocks (16384 threads) exactly covers all work items.

__global__ void init_kernel(float* __restrict__ sums1, float* __restrict__ sums2,
                            int* __restrict__ rs, int* __restrict__ cur,
                            const int* __restrict__ ei, int* __restrict__ flag,
                            const float* __restrict__ W1, const float* __restrict__ W2,
                            const float* __restrict__ W3, unsigned short* __restrict__ Wb1,
                            unsigned short* __restrict__ Wb2, unsigned short* __restrict__ Wb3) {
  int i = blockIdx.x * 256 + threadIdx.x;
  if (i < NSHADOW * 256) { sums1[i] = 0.f; sums2[i] = 0.f; }
  if (i < NBUCK) cur[i] = i * BCAP;
  if (i == 0) rs[N_NODES] = TOT_E;
  if (i < 16384) Wb1[i] = f2bf(W1[i]);
  if (i < 16384) Wb2[i] = f2bf(W2[i]);
  if (i < 8192)  Wb3[i] = f2bf(W3[i]);
  // int64 detection: odd int32 words of first 64 entries all zero => int64
  if (blockIdx.x == 0 && threadIdx.x < 64) {
    int v = ei[2 * threadIdx.x + 1];
    unsigned long long b = __ballot(v != 0);
    if (threadIdx.x == 0) flag[0] = (b == 0ULL) ? 1 : 0;
  }
}

// ---- partition: bucket edges by dst>>7, LDS-sorted coalesced flush -------

__global__ __launch_bounds__(1024) void part_kernel(const int* __restrict__ ei,
    const int* __restrict__ flag, int* __restrict__ cur, unsigned int* __restrict__ part) {
  __shared__ int hist[NBUCK];
  __shared__ int hist2[NBUCK];
  __shared__ int lexcl[NBUCK];
  __shared__ int gbase[NBUCK];
  __shared__ int wtot[8];
  __shared__ unsigned int sorted[EPB];
  int tid = threadIdx.x;
  int e0 = blockIdx.x * EPB;
  for (int i = tid; i < NBUCK; i += 1024) { hist[i] = 0; hist2[i] = 0; }
  __syncthreads();
  bool i64 = flag[0] != 0;
  // pass 1: bucket histogram
  for (int i = tid; i < EPB; i += 1024) {
    int e = e0 + i;
    int d = i64 ? ei[2 * (N_EDGES + e)] : ei[N_EDGES + e];
    atomicAdd(&hist[d >> 7], 1);
  }
  __syncthreads();
  // exclusive scan of hist -> lexcl (NBUCK <= 512: 8 waves)
  if (tid < 512) {
    int lane = tid & 63, w = tid >> 6;
    int h = (tid < NBUCK) ? hist[tid] : 0;
    int v = h;
#pragma unroll
    for (int off = 1; off < 64; off <<= 1) {
      int u = __shfl_up(v, off);
      if (lane >= off) v += u;
    }
    if (lane == 63) wtot[w] = v;
    if (tid < NBUCK) lexcl[tid] = v - h;
  }
  __syncthreads();
  if (tid < NBUCK) {
    int w = tid >> 6, off = 0;
    for (int k = 0; k < w; k++) off += wtot[k];
    lexcl[tid] += off;
    gbase[tid] = atomicAdd(&cur[tid], hist[tid]);   // reserve global range
  }
  __syncthreads();
  // pass 2: stage edges sorted by bucket in LDS
  for (int i = tid; i < EPB; i += 1024) {
    int e = e0 + i;
    int s, d;
    if (i64) { s = ei[2 * e]; d = ei[2 * (N_EDGES + e)]; }
    else     { s = ei[e];     d = ei[N_EDGES + e]; }
    int b = d >> 7;
    int ls = atomicAdd(&hist2[b], 1);
    sorted[lexcl[b] + ls] = ((unsigned int)d << 16) | (unsigned int)s;
  }
  __syncthreads();
  // flush: consecutive tid -> consecutive slots within bucket (coalesced runs)
  for (int j = tid; j < EPB; j += 1024) {
    unsigned int pk = sorted[j];
    int b = (int)(pk >> 23);                      // (d>>16)>>7
    part[gbase[b] + (j - lexcl[b])] = pk;
  }
}

// ---- finalize: per-bucket CSR (ushort), rs, dinv; bscan folded in --------

__global__ __launch_bounds__(256) void fin_kernel(const unsigned int* __restrict__ part,
    const int* __restrict__ cur, unsigned short* __restrict__ csr,
    int* __restrict__ rs, float* __restrict__ dinv) {
  __shared__ int cnt[128], excl[128], iscan[128];
  __shared__ int redbuf[256];
  __shared__ unsigned short ord[BCAP];
  __shared__ unsigned short cls[BCAP + 128];
  int b = blockIdx.x, tid = threadIdx.x;
  int n0 = b * 128;
  int nn = N_NODES - n0; if (nn > 128) nn = 128;
  int ecnt = cur[b] - b * BCAP; if (ecnt > BCAP) ecnt = BCAP;
  int ebase = b * BCAP;
  // csrbase reduction: sum real counts of buckets < b (+128 self-loops each)
  int partial = 0;
  for (int i = tid; i < b; i += 256) partial += cur[i] - i * BCAP + 128;
  redbuf[tid] = partial;
  if (tid < 128) cnt[tid] = 1;                    // self-loop
  __syncthreads();
  if (tid < 128) redbuf[tid] += redbuf[tid + 128];
  for (int i = tid; i < ecnt; i += 256) {
    int dl = (int)((part[ebase + i] >> 16) & 127u);
    ord[i] = (unsigned short)atomicAdd(&cnt[dl], 1);
  }
  __syncthreads();
  // finish reduction with wave 0
  if (tid < 64) {
    int v = redbuf[tid] + redbuf[tid + 64];
#pragma unroll
    for (int off = 32; off; off >>= 1) v += __shfl_xor(v, off);
    redbuf[0] = v;
  }
  // exclusive scan of cnt[0..128): 2 waves
  if (tid >= 128 && tid < 256) {
    int t2 = tid - 128;
    int lane = t2 & 63;
    int c = cnt[t2], v = c;
#pragma unroll
    for (int off = 1; off < 64; off <<= 1) {
      int u = __shfl_up(v, off);
      if (lane >= off) v += u;
    }
    iscan[t2] = v;
  }
  __syncthreads();
  if (tid < 128)
    excl[tid] = iscan[tid] - cnt[tid] + ((tid >= 64) ? iscan[63] : 0);
  __syncthreads();
  int base = redbuf[0];
  // place self-loops then edges
  if (tid < nn) cls[excl[tid]] = (unsigned short)(n0 + tid);
  __syncthreads();
  for (int i = tid; i < ecnt; i += 256) {
    unsigned int pk = part[ebase + i];
    int dl = (int)((pk >> 16) & 127u);
    cls[excl[dl] + ord[i]] = (unsigned short)(pk & 0xffffu);
  }
  __syncthreads();
  int tot = ecnt + nn;
  for (int j = tid; j < tot; j += 256) csr[base + j] = cls[j];
  if (tid < nn) {
    rs[n0 + tid] = base + excl[tid];
    dinv[n0 + tid] = rsqrtf((float)cnt[tid]);
  }
}

// ---- dense matmul with fused A-side BN/ReLU/bf16 cast --------------------
// BN==0: A is fp32 [N][128] raw (layer 1 input x).
// BN==1: A is bf16-packed dwords [N][64] (prev agg out); apply BN+ReLU.
// sums has NSHADOW shadow copies (fused-stats epilogue in agg128); fold here.
// W pre-converted to bf16 (Wb). Epilogue folds dinv. Hb unsegmented [N][OUT].

template <int OUT, int BN>
__global__ __launch_bounds__(256) void mm_kernel(const void* __restrict__ Ain,
    const float* __restrict__ sums, const float* __restrict__ g,
    const float* __restrict__ bt, const unsigned short* __restrict__ Wb,
    const float* __restrict__ dinv, unsigned short* __restrict__ Hb) {
  constexpr int K = 128;
  constexpr int LDW = K + 8;
  __shared__ __align__(16) unsigned short Wl[OUT * LDW];
  __shared__ float scs[128], shs[128];
  int tid = threadIdx.x;
  // stage Wb -> Wl via uint4 (8 ush per chunk; 16 chunks per row, row-aligned)
#pragma unroll
  for (int c = tid; c < OUT * K / 8; c += 256) {
    int row = c >> 4, col = (c & 15) * 8;
    uint4 v = *(const uint4*)(Wb + row * K + col);
    *(uint4*)(Wl + row * LDW + col) = v;
  }
  if (BN && tid < 128) {
    float s = 0.f, qq = 0.f;
#pragma unroll
    for (int c = 0; c < NSHADOW; c++) {
      s  += sums[c * 256 + tid];
      qq += sums[c * 256 + 128 + tid];
    }
    const float inv_n = 1.0f / (float)N_NODES;
    float mean = s * inv_n;
    float var  = qq * inv_n - mean * mean;
    float sc = g[tid] * rsqrtf(var + 1e-5f);
    scs[tid] = sc;
    shs[tid] = bt[tid] - mean * sc;
  }
  __syncthreads();

  int lane = tid & 63;
  int wv = tid >> 6;
  int m = lane & 15, q = lane >> 4;
  long n0 = (long)blockIdx.x * 64 + wv * 16;
  long arow = n0 + m; if (arow > N_NODES - 1) arow = N_NODES - 1;

  short8 a[4];
  if (BN) {
    const unsigned int* A32 = (const unsigned int*)Ain;
#pragma unroll
    for (int kb = 0; kb < 4; kb++) {
      uint4 v = *(const uint4*)(A32 + (size_t)arow * 64 + kb * 16 + q * 4);
      unsigned int vv[4] = {v.x, v.y, v.z, v.w};
      short8 t;
#pragma unroll
      for (int j = 0; j < 4; j++) {
        int ch = kb * 32 + q * 8 + j * 2;
        float lo = bflo(vv[j]) * scs[ch] + shs[ch];
        float hi = bfhi(vv[j]) * scs[ch + 1] + shs[ch + 1];
        lo = fmaxf(lo, 0.f); hi = fmaxf(hi, 0.f);
        t[2 * j] = (short)f2bf(lo); t[2 * j + 1] = (short)f2bf(hi);
      }
      a[kb] = t;
    }
  } else {
    const float* Af = (const float*)Ain;
#pragma unroll
    for (int kb = 0; kb < 4; kb++) {
      const float* p = Af + (size_t)arow * 128 + kb * 32 + q * 8;
      float4 v0 = *(const float4*)(p);
      float4 v1 = *(const float4*)(p + 4);
      short8 t;
      t[0] = (short)f2bf(v0.x); t[1] = (short)f2bf(v0.y);
      t[2] = (short)f2bf(v0.z); t[3] = (short)f2bf(v0.w);
      t[4] = (short)f2bf(v1.x); t[5] = (short)f2bf(v1.y);
      t[6] = (short)f2bf(v1.z); t[7] = (short)f2bf(v1.w);
      a[kb] = t;
    }
  }

  f32x4 acc[OUT / 16];
#pragma unroll
  for (int t = 0; t < OUT / 16; t++) acc[t] = (f32x4){0.f, 0.f, 0.f, 0.f};

#pragma unroll
  for (int ot = 0; ot < OUT / 16; ot++) {
    const unsigned short* wrow = Wl + (size_t)(ot * 16 + m) * LDW + q * 8;
    short8 b0 = *(const short8*)(wrow);
    short8 b1 = *(const short8*)(wrow + 32);
    short8 b2 = *(const short8*)(wrow + 64);
    short8 b3 = *(const short8*)(wrow + 96);
    acc[ot] = __builtin_amdgcn_mfma_f32_16x16x32_bf16(a[0], b0, acc[ot], 0, 0, 0);
    acc[ot] = __builtin_amdgcn_mfma_f32_16x16x32_bf16(a[1], b1, acc[ot], 0, 0, 0);
    acc[ot] = __builtin_amdgcn_mfma_f32_16x16x32_bf16(a[2], b2, acc[ot], 0, 0, 0);
    acc[ot] = __builtin_amdgcn_mfma_f32_16x16x32_bf16(a[3], b3, acc[ot], 0, 0, 0);
  }

  float dn[4];
#pragma unroll
  for (int r = 0; r < 4; r++) {
    long n = n0 + q * 4 + r;
    dn[r] = (n < N_NODES) ? dinv[n] : 0.f;
  }
#pragma unroll
  for (int ot = 0; ot < OUT / 16; ot++) {
#pragma unroll
    for (int r = 0; r < 4; r++) {
      long n = n0 + q * 4 + r;            // D: row = quad*4 + reg, col = lane&15
      if (n < N_NODES) Hb[n * OUT + ot * 16 + m] = f2bf(dn[r] * acc[ot][r]);
    }
  }
}

// ---- aggregation (128ch) + FUSED BN stats --------------------------------
// Gather structure unchanged from R3 (proven at the bandwidth floor):
// 2 nodes/wave interleaved, 32 lanes x dwordx2, 2 edge slots, 16/8/4 tails.
// NEW: post-loop stats epilogue. Each thread holds the 4 rounded bf16
// channels of exactly one node -> LDS atomicAdd into 128-ch sum/sq slots ->
// one global atomicAdd per channel per block into NSHADOW shadow copies
// (sums[shadow*256 + ch] / [.. + 128 + ch]). This is NOT the failed R6/R10/
// R12 form (persistent in-loop accumulators); the gather loop is untouched.

#define LDA(k) uint2 vA##k = *(const uint2*)(H32 + (size_t)eA##k * 64 + 2 * l)
#define LDB(k) uint2 vB##k = *(const uint2*)(H32 + (size_t)eB##k * 64 + 2 * l)
#define ACA(k) { a0 += bflo(vA##k.x); a1 += bfhi(vA##k.x); \
                 a2 += bflo(vA##k.y); a3 += bfhi(vA##k.y); }
#define ACB(k) { b0 += bflo(vB##k.x); b1 += bfhi(vB##k.x); \
                 b2 += bflo(vB##k.y); b3 += bfhi(vB##k.y); }

__global__ __launch_bounds__(256, 4) void agg128_kernel(const unsigned int* __restrict__ H32,
    const int* __restrict__ rs, const unsigned short* __restrict__ csr,
    const float* __restrict__ dinv, const float* __restrict__ bias,
    unsigned int* __restrict__ outb, float* __restrict__ sums) {
  __shared__ float lsum[128], lsq[128];
  int tid = threadIdx.x;
  if (tid < 128) { lsum[tid] = 0.f; lsq[tid] = 0.f; }
  __syncthreads();
  int l = tid & 31;                             // dword-pair index in row
  int g = (tid >> 5) & 1;                       // edge slot
  int nA = blockIdx.x * 8 + (tid >> 6) * 2;     // wave-uniform
  int nB = nA + 1;
  int begA = __builtin_amdgcn_readfirstlane(rs[nA]);
  int endA = __builtin_amdgcn_readfirstlane(rs[nA + 1]);  // == begB
  int endB = __builtin_amdgcn_readfirstlane(rs[nB + 1]);
  float a0 = 0.f, a1 = 0.f, a2 = 0.f, a3 = 0.f;
  float b0 = 0.f, b1 = 0.f, b2 = 0.f, b3 = 0.f;
  int jA = begA, jB = endA;
  // interleaved 16+16 (32 gathers in flight)
  while (jA + 16 <= endA && jB + 16 <= endB) {
    int eA0 = csr[jA + g],      eA1 = csr[jA + 2 + g],  eA2 = csr[jA + 4 + g],  eA3 = csr[jA + 6 + g];
    int eA4 = csr[jA + 8 + g],  eA5 = csr[jA + 10 + g], eA6 = csr[jA + 12 + g], eA7 = csr[jA + 14 + g];
    int eB0 = csr[jB + g],      eB1 = csr[jB + 2 + g],  eB2 = csr[jB + 4 + g],  eB3 = csr[jB + 6 + g];
    int eB4 = csr[jB + 8 + g],  eB5 = csr[jB + 10 + g], eB6 = csr[jB + 12 + g], eB7 = csr[jB + 14 + g];
    LDA(0); LDA(1); LDA(2); LDA(3); LDA(4); LDA(5); LDA(6); LDA(7);
    LDB(0); LDB(1); LDB(2); LDB(3); LDB(4); LDB(5); LDB(6); LDB(7);
    ACA(0); ACA(1); ACA(2); ACA(3); ACA(4); ACA(5); ACA(6); ACA(7);
    ACB(0); ACB(1); ACB(2); ACB(3); ACB(4); ACB(5); ACB(6); ACB(7);
    jA += 16; jB += 16;
  }
  // interleaved 8+8
  while (jA + 8 <= endA && jB + 8 <= endB) {
    int eA0 = csr[jA + g], eA1 = csr[jA + 2 + g], eA2 = csr[jA + 4 + g], eA3 = csr[jA + 6 + g];
    int eB0 = csr[jB + g], eB1 = csr[jB + 2 + g], eB2 = csr[jB + 4 + g], eB3 = csr[jB + 6 + g];
    LDA(0); LDA(1); LDA(2); LDA(3);
    LDB(0); LDB(1); LDB(2); LDB(3);
    ACA(0); ACA(1); ACA(2); ACA(3);
    ACB(0); ACB(1); ACB(2); ACB(3);
    jA += 8; jB += 8;
  }
  // finish node A (16/8/4/pairs, index order preserved)
  for (; jA + 16 <= endA; jA += 16) {
    int eA0 = csr[jA + g],      eA1 = csr[jA + 2 + g],  eA2 = csr[jA + 4 + g],  eA3 = csr[jA + 6 + g];
    int eA4 = csr[jA + 8 + g],  eA5 = csr[jA + 10 + g], eA6 = csr[jA + 12 + g], eA7 = csr[jA + 14 + g];
    LDA(0); LDA(1); LDA(2); LDA(3); LDA(4); LDA(5); LDA(6); LDA(7);
    ACA(0); ACA(1); ACA(2); ACA(3); ACA(4); ACA(5); ACA(6); ACA(7);
  }
  if (jA + 8 <= endA) {
    int eA0 = csr[jA + g], eA1 = csr[jA + 2 + g], eA2 = csr[jA + 4 + g], eA3 = csr[jA + 6 + g];
    LDA(0); LDA(1); LDA(2); LDA(3);
    ACA(0); ACA(1); ACA(2); ACA(3);
    jA += 8;
  }
  if (jA + 4 <= endA) {
    int eA0 = csr[jA + g], eA1 = csr[jA + 2 + g];
    LDA(0); LDA(1);
    ACA(0); ACA(1);
    jA += 4;
  }
  for (int t = jA + g; t < endA; t += 2) {
    int eA0 = csr[t];
    LDA(0);
    ACA(0);
  }
  // finish node B
  for (; jB + 16 <= endB; jB += 16) {
    int eB0 = csr[jB + g],      eB1 = csr[jB + 2 + g],  eB2 = csr[jB + 4 + g],  eB3 = csr[jB + 6 + g];
    int eB4 = csr[jB + 8 + g],  eB5 = csr[jB + 10 + g], eB6 = csr[jB + 12 + g], eB7 = csr[jB + 14 + g];
    LDB(0); LDB(1); LDB(2); LDB(3); LDB(4); LDB(5); LDB(6); LDB(7);
    ACB(0); ACB(1); ACB(2); ACB(3); ACB(4); ACB(5); ACB(6); ACB(7);
  }
  if (jB + 8 <= endB) {
    int eB0 = csr[jB + g], eB1 = csr[jB + 2 + g], eB2 = csr[jB + 4 + g], eB3 = csr[jB + 6 + g];
    LDB(0); LDB(1); LDB(2); LDB(3);
    ACB(0); ACB(1); ACB(2); ACB(3);
    jB += 8;
  }
  if (jB + 4 <= endB) {
    int eB0 = csr[jB + g], eB1 = csr[jB + 2 + g];
    LDB(0); LDB(1);
    ACB(0); ACB(1);
    jB += 4;
  }
  for (int t = jB + g; t < endB; t += 2) {
    int eB0 = csr[t];
    LDB(0);
    ACB(0);
  }
  // cross-slot reduce (lanes g=0 and g=1 hold complementary partials)
  a0 += __shfl_xor(a0, 32); a1 += __shfl_xor(a1, 32);
  a2 += __shfl_xor(a2, 32); a3 += __shfl_xor(a3, 32);
  b0 += __shfl_xor(b0, 32); b1 += __shfl_xor(b1, 32);
  b2 += __shfl_xor(b2, 32); b3 += __shfl_xor(b3, 32);
  const float4 bb = *(const float4*)(bias + 4 * l);
  // each half-wave finalizes its node (g=0 -> A, g=1 -> B)
  int nd = g ? nB : nA;
  float s0 = g ? b0 : a0, s1 = g ? b1 : a1, s2 = g ? b2 : a2, s3 = g ? b3 : a3;
  float di = dinv[nd];
  float r0 = s0 * di + bb.x, r1 = s1 * di + bb.y;
  float r2 = s2 * di + bb.z, r3 = s3 * di + bb.w;
  uint2 o;
  o.x = (unsigned int)f2bf(r0) | ((unsigned int)f2bf(r1) << 16);
  o.y = (unsigned int)f2bf(r2) | ((unsigned int)f2bf(r3) << 16);
  *(uint2*)(outb + (size_t)nd * 64 + 2 * l) = o;
  // fused BN stats on the rounded values (matches old stats_kernel input)
  float x0 = bflo(o.x), x1 = bfhi(o.x), x2 = bflo(o.y), x3 = bfhi(o.y);
  int c = 4 * l;
  atomicAdd(&lsum[c],     x0); atomicAdd(&lsq[c],     x0 * x0);
  atomicAdd(&lsum[c + 1], x1); atomicAdd(&lsq[c + 1], x1 * x1);
  atomicAdd(&lsum[c + 2], x2); atomicAdd(&lsq[c + 2], x2 * x2);
  atomicAdd(&lsum[c + 3], x3); atomicAdd(&lsq[c + 3], x3 * x3);
  __syncthreads();
  if (tid < 128) {
    int sh = (blockIdx.x & (NSHADOW - 1)) * 256;
    atomicAdd(&sums[sh + tid], lsum[tid]);
    atomicAdd(&sums[sh + 128 + tid], lsq[tid]);
  }
}

// 64ch final layer: each 32-lane half handles 2 nodes interleaved (4 nodes
// per wave, 16 per block). dword per lane (2ch), single accum pair per node.

#define LDA64(k) unsigned int vA##k = H32[(size_t)eA##k * 32 + l]
#define LDB64(k) unsigned int vB##k = H32[(size_t)eB##k * 32 + l]
#define ACA64(k) { ax += bflo(vA##k); ay += bfhi(vA##k); }
#define ACB64(k) { bx += bflo(vB##k); by += bfhi(vB##k); }

__global__ __launch_bounds__(256, 4) void agg64_kernel(const unsigned int* __restrict__ H32,
    const int* __restrict__ rs, const unsigned short* __restrict__ csr,
    const float* __restrict__ dinv, const float* __restrict__ bias,
    float* __restrict__ out) {
  int l = threadIdx.x & 31;                     // dword index in row
  int nA = blockIdx.x * 16 + (threadIdx.x >> 5) * 2;
  int nB = nA + 1;
  int begA = rs[nA], endA = rs[nA + 1], endB = rs[nB + 1];
  float ax = 0.f, ay = 0.f, bx = 0.f, by = 0.f;
  int jA = begA, jB = endA;
  // interleaved 8+8 (16 loads in flight per half-wave)
  while (jA + 8 <= endA && jB + 8 <= endB) {
    int eA0 = csr[jA],     eA1 = csr[jA + 1], eA2 = csr[jA + 2], eA3 = csr[jA + 3];
    int eA4 = csr[jA + 4], eA5 = csr[jA + 5], eA6 = csr[jA + 6], eA7 = csr[jA + 7];
    int eB0 = csr[jB],     eB1 = csr[jB + 1], eB2 = csr[jB + 2], eB3 = csr[jB + 3];
    int eB4 = csr[jB + 4], eB5 = csr[jB + 5], eB6 = csr[jB + 6], eB7 = csr[jB + 7];
    LDA64(0); LDA64(1); LDA64(2); LDA64(3); LDA64(4); LDA64(5); LDA64(6); LDA64(7);
    LDB64(0); LDB64(1); LDB64(2); LDB64(3); LDB64(4); LDB64(5); LDB64(6); LDB64(7);
    ACA64(0); ACA64(1); ACA64(2); ACA64(3); ACA64(4); ACA64(5); ACA64(6); ACA64(7);
    ACB64(0); ACB64(1); ACB64(2); ACB64(3); ACB64(4); ACB64(5); ACB64(6); ACB64(7);
    jA += 8; jB += 8;
  }
  // interleaved 4+4
  while (jA + 4 <= endA && jB + 4 <= endB) {
    int eA0 = csr[jA], eA1 = csr[jA + 1], eA2 = csr[jA + 2], eA3 = csr[jA + 3];
    int eB0 = csr[jB], eB1 = csr[jB + 1], eB2 = csr[jB + 2], eB3 = csr[jB + 3];
    LDA64(0); LDA64(1); LDA64(2); LDA64(3);
    LDB64(0); LDB64(1); LDB64(2); LDB64(3);
    ACA64(0); ACA64(1); ACA64(2); ACA64(3);
    ACB64(0); ACB64(1); ACB64(2); ACB64(3);
    jA += 4; jB += 4;
  }
  // finish node A
  for (; jA + 8 <= endA; jA += 8) {
    int eA0 = csr[jA],     eA1 = csr[jA + 1], eA2 = csr[jA + 2], eA3 = csr[jA + 3];
    int eA4 = csr[jA + 4], eA5 = csr[jA + 5], eA6 = csr[jA + 6], eA7 = csr[jA + 7];
    LDA64(0); LDA64(1); LDA64(2); LDA64(3); LDA64(4); LDA64(5); LDA64(6); LDA64(7);
    ACA64(0); ACA64(1); ACA64(2); ACA64(3); ACA64(4); ACA64(5); ACA64(6); ACA64(7);
  }
  if (jA + 4 <= endA) {
    int eA0 = csr[jA], eA1 = csr[jA + 1], eA2 = csr[jA + 2], eA3 = csr[jA + 3];
    LDA64(0); LDA64(1); LDA64(2); LDA64(3);
    ACA64(0); ACA64(1); ACA64(2); ACA64(3);
    jA += 4;
  }
  for (; jA < endA; ++jA) {
    int eA0 = csr[jA];
    LDA64(0);
    ACA64(0);
  }
  // finish node B
  for (; jB + 8 <= endB; jB += 8) {
    int eB0 = csr[jB],     eB1 = csr[jB + 1], eB2 = csr[jB + 2], eB3 = csr[jB + 3];
    int eB4 = csr[jB + 4], eB5 = csr[jB + 5], eB6 = csr[jB + 6], eB7 = csr[jB + 7];
    LDB64(0); LDB64(1); LDB64(2); LDB64(3); LDB64(4); LDB64(5); LDB64(6); LDB64(7);
    ACB64(0); ACB64(1); ACB64(2); ACB64(3); ACB64(4); ACB64(5); ACB64(6); ACB64(7);
  }
  if (jB + 4 <= endB) {
    int eB0 = csr[jB], eB1 = csr[jB + 1], eB2 = csr[jB + 2], eB3 = csr[jB + 3];
    LDB64(0); LDB64(1); LDB64(2); LDB64(3);
    ACB64(0); ACB64(1); ACB64(2); ACB64(3);
    jB += 4;
  }
  for (; jB < endB; ++jB) {
    int eB0 = csr[jB];
    LDB64(0);
    ACB64(0);
  }
  int c = l * 2;
  float diA = dinv[nA], diB = dinv[nB];
  float bx0 = bias[c], bx1 = bias[c + 1];
  out[(size_t)nA * 64 + c]     = ax * diA + bx0;
  out[(size_t)nA * 64 + c + 1] = ay * diA + bx1;
  out[(size_t)nB * 64 + c]     = bx * diB + bx0;
  out[(size_t)nB * 64 + c + 1] = by * diB + bx1;
}

// ---- driver --------------------------------------------------------------

extern "C" void kernel_launch(void* const* d_in, const int* in_sizes, int n_in,
                              void* d_out, int out_size, void* d_ws, size_t ws_size,
                              hipStream_t stream) {
  const float* x   = (const float*)d_in[0];
  const int*   ei  = (const int*)d_in[1];
  const float* W1  = (const float*)d_in[2];
  const float* b1  = (const float*)d_in[3];
  const float* W2  = (const float*)d_in[4];
  const float* b2  = (const float*)d_in[5];
  const float* W3  = (const float*)d_in[6];
  const float* b3  = (const float*)d_in[7];
  const float* g1  = (const float*)d_in[8];
  const float* bt1 = (const float*)d_in[9];
  const float* g2  = (const float*)d_in[10];
  const float* bt2 = (const float*)d_in[11];
  float* out = (float*)d_out;

  char* p = (char*)d_ws;
  auto carve = [&](size_t bytes) { char* r = p; p += (bytes + 255) & ~(size_t)255; return r; };
  int*   rs      = (int*)  carve((size_t)(N_NODES + 1) * 4);
  float* dinv    = (float*)carve((size_t)N_NODES * 4);
  int*   cur     = (int*)  carve((size_t)NBUCK * 4);
  unsigned int* part = (unsigned int*)carve((size_t)NBUCK * BCAP * 4);
  unsigned short* csr = (unsigned short*)carve((size_t)(TOT_E + 32) * 2);
  float* sums1   = (float*)carve((size_t)NSHADOW * 256 * 4);
  float* sums2   = (float*)carve((size_t)NSHADOW * 256 * 4);
  int*   flag    = (int*)  carve(256);
  unsigned short* Wb1 = (unsigned short*)carve(16384 * 2);
  unsigned short* Wb2 = (unsigned short*)carve(16384 * 2);
  unsigned short* Wb3 = (unsigned short*)carve(8192 * 2);
  unsigned short* Hb = (unsigned short*)carve((size_t)(N_NODES + 1) * 128 * 2);
  unsigned int*   Bb = (unsigned int*)  carve((size_t)N_NODES * 64 * 4);

  init_kernel<<<64, 256, 0, stream>>>(sums1, sums2, rs, cur, ei, flag,
                                      W1, W2, W3, Wb1, Wb2, Wb3);
  part_kernel<<<PART_BLOCKS, 1024, 0, stream>>>(ei, flag, cur, part);
  fin_kernel<<<NBUCK, 256, 0, stream>>>(part, cur, csr, rs, dinv);

  // layer 1: mm(x) -> agg(+stats1)
  mm_kernel<128, 0><<<(N_NODES + 63) / 64, 256, 0, stream>>>(x, sums1, g1, bt1, Wb1, dinv, Hb);
  agg128_kernel<<<N_NODES / 8, 256, 0, stream>>>((const unsigned int*)Hb, rs, csr, dinv, b1, Bb, sums1);

  // layer 2: mm(BN1(Bb)) -> agg(+stats2)
  mm_kernel<128, 1><<<(N_NODES + 63) / 64, 256, 0, stream>>>(Bb, sums1, g1, bt1, Wb2, dinv, Hb);
  agg128_kernel<<<N_NODES / 8, 256, 0, stream>>>((const unsigned int*)Hb, rs, csr, dinv, b2, Bb, sums2);

  // layer 3: mm(BN2(Bb)) -> agg -> out (fp32)
  mm_kernel<64, 1><<<(N_NODES + 63) / 64, 256, 0, stream>>>(Bb, sums2, g2, bt2, Wb3, dinv, Hb);
  agg64_kernel<<<N_NODES / 16, 256, 0, stream>>>((const unsigned int*)Hb, rs, csr, dinv, b3, out);
}

// Round 6
// 290.707 us; speedup vs baseline: 1.1628x; 1.1628x over previous
//
#include <hip/hip_runtime.h>
#include <hip/hip_bf16.h>

#define N_NODES 50000
#define N_EDGES 800000
#define TOT_E   (N_EDGES + N_NODES)
#define NBUCK   ((N_NODES + 127) / 128)     // 391 buckets of 128 dst nodes
#define BCAP    3072                         // bucket capacity (avg 2048, max ~2300)
#define PART_BLOCKS 256
#define EPB     (N_EDGES / PART_BLOCKS)      // 3125 edges per partition block

typedef __attribute__((ext_vector_type(8))) short short8;
typedef __attribute__((ext_vector_type(4))) float f32x4;

__device__ __forceinline__ unsigned short f2bf(float f) {
  union { float f; unsigned int u; } x; x.f = f;
  unsigned int u = x.u;
  unsigned int r = (u + 0x7FFFu + ((u >> 16) & 1u)) >> 16;  // RNE
  return (unsigned short)r;
}
__device__ __forceinline__ float bflo(unsigned int v) {   // bf16 in low half
  union { unsigned int u; float f; } x; x.u = v << 16; return x.f;
}
__device__ __forceinline__ float bfhi(unsigned int v) {   // bf16 in high half
  union { unsigned int u; float f; } x; x.u = v & 0xffff0000u; return x.f;
}

// ---- init: zero sums/cursors, detect dtype, pre-convert W -> bf16 --------
// Grid = 64 blocks (16384 threads) exactly covers all work items.

__global__ void init_kernel(float* __restrict__ sums1, float* __restrict__ sums2,
                            int* __restrict__ rs, int* __restrict__ cur,
                            const int* __restrict__ ei, int* __restrict__ flag,
                            const float* __restrict__ W1, const float* __restrict__ W2,
                            const float* __restrict__ W3, unsigned short* __restrict__ Wb1,
                            unsigned short* __restrict__ Wb2, unsigned short* __restrict__ Wb3) {
  int i = blockIdx.x * 256 + threadIdx.x;
  if (i < 256) { sums1[i] = 0.f; sums2[i] = 0.f; }
  if (i < NBUCK) cur[i] = i * BCAP;
  if (i == 0) rs[N_NODES] = TOT_E;
  if (i < 16384) Wb1[i] = f2bf(W1[i]);
  if (i < 16384) Wb2[i] = f2bf(W2[i]);
  if (i < 8192)  Wb3[i] = f2bf(W3[i]);
  // int64 detection: odd int32 words of first 64 entries all zero => int64
  if (blockIdx.x == 0 && threadIdx.x < 64) {
    int v = ei[2 * threadIdx.x + 1];
    unsigned long long b = __ballot(v != 0);
    if (threadIdx.x == 0) flag[0] = (b == 0ULL) ? 1 : 0;
  }
}

// ---- partition: bucket edges by dst>>7, LDS-sorted coalesced flush -------

__global__ __launch_bounds__(1024) void part_kernel(const int* __restrict__ ei,
    const int* __restrict__ flag, int* __restrict__ cur, unsigned int* __restrict__ part) {
  __shared__ int hist[NBUCK];
  __shared__ int hist2[NBUCK];
  __shared__ int lexcl[NBUCK];
  __shared__ int gbase[NBUCK];
  __shared__ int wtot[8];
  __shared__ unsigned int sorted[EPB];
  int tid = threadIdx.x;
  int e0 = blockIdx.x * EPB;
  for (int i = tid; i < NBUCK; i += 1024) { hist[i] = 0; hist2[i] = 0; }
  __syncthreads();
  bool i64 = flag[0] != 0;
  // pass 1: bucket histogram
  for (int i = tid; i < EPB; i += 1024) {
    int e = e0 + i;
    int d = i64 ? ei[2 * (N_EDGES + e)] : ei[N_EDGES + e];
    atomicAdd(&hist[d >> 7], 1);
  }
  __syncthreads();
  // exclusive scan of hist -> lexcl (NBUCK <= 512: 8 waves)
  if (tid < 512) {
    int lane = tid & 63, w = tid >> 6;
    int h = (tid < NBUCK) ? hist[tid] : 0;
    int v = h;
#pragma unroll
    for (int off = 1; off < 64; off <<= 1) {
      int u = __shfl_up(v, off);
      if (lane >= off) v += u;
    }
    if (lane == 63) wtot[w] = v;
    if (tid < NBUCK) lexcl[tid] = v - h;
  }
  __syncthreads();
  if (tid < NBUCK) {
    int w = tid >> 6, off = 0;
    for (int k = 0; k < w; k++) off += wtot[k];
    lexcl[tid] += off;
    gbase[tid] = atomicAdd(&cur[tid], hist[tid]);   // reserve global range
  }
  __syncthreads();
  // pass 2: stage edges sorted by bucket in LDS
  for (int i = tid; i < EPB; i += 1024) {
    int e = e0 + i;
    int s, d;
    if (i64) { s = ei[2 * e]; d = ei[2 * (N_EDGES + e)]; }
    else     { s = ei[e];     d = ei[N_EDGES + e]; }
    int b = d >> 7;
    int ls = atomicAdd(&hist2[b], 1);
    sorted[lexcl[b] + ls] = ((unsigned int)d << 16) | (unsigned int)s;
  }
  __syncthreads();
  // flush: consecutive tid -> consecutive slots within bucket (coalesced runs)
  for (int j = tid; j < EPB; j += 1024) {
    unsigned int pk = sorted[j];
    int b = (int)(pk >> 23);                      // (d>>16)>>7
    part[gbase[b] + (j - lexcl[b])] = pk;
  }
}

// ---- finalize: per-bucket CSR (ushort), rs, dinv; bscan folded in --------
// R5 CHANGE: per-node adjacency ordered by SOURCE OCTILE (src/6250) via a
// counting sort with 8 buckets per node (1024 LDS counters + 1024-wide scan).
// All concurrently-resident agg waves then walk ascending-src order -> a
// synchronized sweep over H -> per-XCD-L2-resident instantaneous working set.
// agg kernels are byte-identical; only the csr entry order changes.

__global__ __launch_bounds__(256) void fin_kernel(const unsigned int* __restrict__ part,
    const int* __restrict__ cur, unsigned short* __restrict__ csr,
    int* __restrict__ rs, float* __restrict__ dinv) {
  __shared__ int cnt8[1024];                    // [dl][oct]
  __shared__ int excl8[1024];
  __shared__ int wsum[4];
  __shared__ int gtot;
  __shared__ int redbuf[256];
  __shared__ unsigned short ord[BCAP];
  __shared__ unsigned short cls[BCAP + 128];
  int b = blockIdx.x, tid = threadIdx.x;
  int n0 = b * 128;
  int nn = N_NODES - n0; if (nn > 128) nn = 128;
  int ecnt = cur[b] - b * BCAP; if (ecnt > BCAP) ecnt = BCAP;
  int ebase = b * BCAP;
  // csrbase reduction: sum real counts of buckets < b (+128 self-loops each)
  int partial = 0;
  for (int i = tid; i < b; i += 256) partial += cur[i] - i * BCAP + 128;
  redbuf[tid] = partial;
  for (int i = tid; i < 1024; i += 256) cnt8[i] = 0;
  __syncthreads();
  if (tid < 128) redbuf[tid] += redbuf[tid + 128];
  // count: self-loop (src = node itself) + edges, bucketed by src octile
  int sord = 0;
  if (tid < nn) sord = atomicAdd(&cnt8[tid * 8 + (n0 + tid) / 6250], 1);
  for (int i = tid; i < ecnt; i += 256) {
    unsigned int pk = part[ebase + i];
    int dl = (int)((pk >> 16) & 127u);
    int src = (int)(pk & 0xffffu);
    ord[i] = (unsigned short)atomicAdd(&cnt8[dl * 8 + src / 6250], 1);
  }
  __syncthreads();
  // finish csrbase reduction with wave 0
  if (tid < 64) {
    int v = redbuf[tid] + redbuf[tid + 64];
#pragma unroll
    for (int off = 32; off; off >>= 1) v += __shfl_xor(v, off);
    redbuf[0] = v;
  }
  // exclusive scan of cnt8[0..1024): 4 entries/thread, 4-wave scan
  int c0 = cnt8[4 * tid], c1 = cnt8[4 * tid + 1];
  int c2 = cnt8[4 * tid + 2], c3 = cnt8[4 * tid + 3];
  int s = c0 + c1 + c2 + c3;
  int lane = tid & 63, w = tid >> 6;
  int v = s;
#pragma unroll
  for (int off = 1; off < 64; off <<= 1) {
    int u = __shfl_up(v, off);
    if (lane >= off) v += u;
  }
  if (lane == 63) wsum[w] = v;
  __syncthreads();
  int woff = 0;
  for (int k = 0; k < w; k++) woff += wsum[k];
  int ex = woff + v - s;
  excl8[4 * tid]     = ex;
  excl8[4 * tid + 1] = ex + c0;
  excl8[4 * tid + 2] = ex + c0 + c1;
  excl8[4 * tid + 3] = ex + c0 + c1 + c2;
  if (tid == 255) gtot = ex + s;
  __syncthreads();
  int base = redbuf[0];
  // place self-loops then edges at (node, octile, arrival) positions
  if (tid < nn)
    cls[excl8[tid * 8 + (n0 + tid) / 6250] + sord] = (unsigned short)(n0 + tid);
  for (int i = tid; i < ecnt; i += 256) {
    unsigned int pk = part[ebase + i];
    int dl = (int)((pk >> 16) & 127u);
    int src = (int)(pk & 0xffffu);
    cls[excl8[dl * 8 + src / 6250] + ord[i]] = (unsigned short)src;
  }
  __syncthreads();
  int tot = ecnt + nn;
  for (int j = tid; j < tot; j += 256) csr[base + j] = cls[j];
  if (tid < nn) {
    int st = excl8[tid * 8];
    int en = (tid < 127) ? excl8[(tid + 1) * 8] : gtot;
    rs[n0 + tid] = base + st;
    dinv[n0 + tid] = rsqrtf((float)(en - st));
  }
}

// ---- dense matmul with fused A-side BN/ReLU/bf16 cast --------------------
// BN==0: A is fp32 [N][128] raw (layer 1 input x).
// BN==1: A is bf16-packed dwords [N][64] (prev agg out); apply BN+ReLU.
// W pre-converted to bf16 (Wb). Epilogue folds dinv. Hb unsegmented [N][OUT].

template <int OUT, int BN>
__global__ __launch_bounds__(256) void mm_kernel(const void* __restrict__ Ain,
    const float* __restrict__ sums, const float* __restrict__ g,
    const float* __restrict__ bt, const unsigned short* __restrict__ Wb,
    const float* __restrict__ dinv, unsigned short* __restrict__ Hb) {
  constexpr int K = 128;
  constexpr int LDW = K + 8;
  __shared__ __align__(16) unsigned short Wl[OUT * LDW];
  __shared__ float scs[128], shs[128];
  int tid = threadIdx.x;
  // stage Wb -> Wl via uint4 (8 ush per chunk; 16 chunks per row, row-aligned)
#pragma unroll
  for (int c = tid; c < OUT * K / 8; c += 256) {
    int row = c >> 4, col = (c & 15) * 8;
    uint4 v = *(const uint4*)(Wb + row * K + col);
    *(uint4*)(Wl + row * LDW + col) = v;
  }
  if (BN && tid < 128) {
    const float inv_n = 1.0f / (float)N_NODES;
    float mean = sums[tid] * inv_n;
    float var  = sums[128 + tid] * inv_n - mean * mean;
    float sc = g[tid] * rsqrtf(var + 1e-5f);
    scs[tid] = sc;
    shs[tid] = bt[tid] - mean * sc;
  }
  __syncthreads();

  int lane = tid & 63;
  int wv = tid >> 6;
  int m = lane & 15, q = lane >> 4;
  long n0 = (long)blockIdx.x * 64 + wv * 16;
  long arow = n0 + m; if (arow > N_NODES - 1) arow = N_NODES - 1;

  short8 a[4];
  if (BN) {
    const unsigned int* A32 = (const unsigned int*)Ain;
#pragma unroll
    for (int kb = 0; kb < 4; kb++) {
      uint4 v = *(const uint4*)(A32 + (size_t)arow * 64 + kb * 16 + q * 4);
      unsigned int vv[4] = {v.x, v.y, v.z, v.w};
      short8 t;
#pragma unroll
      for (int j = 0; j < 4; j++) {
        int ch = kb * 32 + q * 8 + j * 2;
        float lo = bflo(vv[j]) * scs[ch] + shs[ch];
        float hi = bfhi(vv[j]) * scs[ch + 1] + shs[ch + 1];
        lo = fmaxf(lo, 0.f); hi = fmaxf(hi, 0.f);
        t[2 * j] = (short)f2bf(lo); t[2 * j + 1] = (short)f2bf(hi);
      }
      a[kb] = t;
    }
  } else {
    const float* Af = (const float*)Ain;
#pragma unroll
    for (int kb = 0; kb < 4; kb++) {
      const float* p = Af + (size_t)arow * 128 + kb * 32 + q * 8;
      float4 v0 = *(const float4*)(p);
      float4 v1 = *(const float4*)(p + 4);
      short8 t;
      t[0] = (short)f2bf(v0.x); t[1] = (short)f2bf(v0.y);
      t[2] = (short)f2bf(v0.z); t[3] = (short)f2bf(v0.w);
      t[4] = (short)f2bf(v1.x); t[5] = (short)f2bf(v1.y);
      t[6] = (short)f2bf(v1.z); t[7] = (short)f2bf(v1.w);
      a[kb] = t;
    }
  }

  f32x4 acc[OUT / 16];
#pragma unroll
  for (int t = 0; t < OUT / 16; t++) acc[t] = (f32x4){0.f, 0.f, 0.f, 0.f};

#pragma unroll
  for (int ot = 0; ot < OUT / 16; ot++) {
    const unsigned short* wrow = Wl + (size_t)(ot * 16 + m) * LDW + q * 8;
    short8 b0 = *(const short8*)(wrow);
    short8 b1 = *(const short8*)(wrow + 32);
    short8 b2 = *(const short8*)(wrow + 64);
    short8 b3 = *(const short8*)(wrow + 96);
    acc[ot] = __builtin_amdgcn_mfma_f32_16x16x32_bf16(a[0], b0, acc[ot], 0, 0, 0);
    acc[ot] = __builtin_amdgcn_mfma_f32_16x16x32_bf16(a[1], b1, acc[ot], 0, 0, 0);
    acc[ot] = __builtin_amdgcn_mfma_f32_16x16x32_bf16(a[2], b2, acc[ot], 0, 0, 0);
    acc[ot] = __builtin_amdgcn_mfma_f32_16x16x32_bf16(a[3], b3, acc[ot], 0, 0, 0);
  }

  float dn[4];
#pragma unroll
  for (int r = 0; r < 4; r++) {
    long n = n0 + q * 4 + r;
    dn[r] = (n < N_NODES) ? dinv[n] : 0.f;
  }
#pragma unroll
  for (int ot = 0; ot < OUT / 16; ot++) {
#pragma unroll
    for (int r = 0; r < 4; r++) {
      long n = n0 + q * 4 + r;            // D: row = quad*4 + reg, col = lane&15
      if (n < N_NODES) Hb[n * OUT + ot * 16 + m] = f2bf(dn[r] * acc[ot][r]);
    }
  }
}

// ---- aggregation (128ch): out[i] = dinv[i] * sum_j Hb[s_j] + bias --------
// R3 structure (proven): 2 nodes/wave interleaved ladders, 32 lanes x
// dwordx2 per row, 2 edge slots (g), 16/8/4 tails, wave-uniform scalar loop.
// launch_bounds(256,4): VGPR cap 128. NO fused stats (R4 post-mortem:
// global atomic fan-in to small buffers costs ~50us).

#define LDA(k) uint2 vA##k = *(const uint2*)(H32 + (size_t)eA##k * 64 + 2 * l)
#define LDB(k) uint2 vB##k = *(const uint2*)(H32 + (size_t)eB##k * 64 + 2 * l)
#define ACA(k) { a0 += bflo(vA##k.x); a1 += bfhi(vA##k.x); \
                 a2 += bflo(vA##k.y); a3 += bfhi(vA##k.y); }
#define ACB(k) { b0 += bflo(vB##k.x); b1 += bfhi(vB##k.x); \
                 b2 += bflo(vB##k.y); b3 += bfhi(vB##k.y); }

__global__ __launch_bounds__(256, 4) void agg128_kernel(const unsigned int* __restrict__ H32,
    const int* __restrict__ rs, const unsigned short* __restrict__ csr,
    const float* __restrict__ dinv, const float* __restrict__ bias,
    unsigned int* __restrict__ outb) {
  int l = threadIdx.x & 31;                     // dword-pair index in row
  int g = (threadIdx.x >> 5) & 1;               // edge slot
  int nA = blockIdx.x * 8 + (threadIdx.x >> 6) * 2;   // wave-uniform
  int nB = nA + 1;
  int begA = __builtin_amdgcn_readfirstlane(rs[nA]);
  int endA = __builtin_amdgcn_readfirstlane(rs[nA + 1]);  // == begB
  int endB = __builtin_amdgcn_readfirstlane(rs[nB + 1]);
  float a0 = 0.f, a1 = 0.f, a2 = 0.f, a3 = 0.f;
  float b0 = 0.f, b1 = 0.f, b2 = 0.f, b3 = 0.f;
  int jA = begA, jB = endA;
  // interleaved 16+16 (32 gathers in flight)
  while (jA + 16 <= endA && jB + 16 <= endB) {
    int eA0 = csr[jA + g],      eA1 = csr[jA + 2 + g],  eA2 = csr[jA + 4 + g],  eA3 = csr[jA + 6 + g];
    int eA4 = csr[jA + 8 + g],  eA5 = csr[jA + 10 + g], eA6 = csr[jA + 12 + g], eA7 = csr[jA + 14 + g];
    int eB0 = csr[jB + g],      eB1 = csr[jB + 2 + g],  eB2 = csr[jB + 4 + g],  eB3 = csr[jB + 6 + g];
    int eB4 = csr[jB + 8 + g],  eB5 = csr[jB + 10 + g], eB6 = csr[jB + 12 + g], eB7 = csr[jB + 14 + g];
    LDA(0); LDA(1); LDA(2); LDA(3); LDA(4); LDA(5); LDA(6); LDA(7);
    LDB(0); LDB(1); LDB(2); LDB(3); LDB(4); LDB(5); LDB(6); LDB(7);
    ACA(0); ACA(1); ACA(2); ACA(3); ACA(4); ACA(5); ACA(6); ACA(7);
    ACB(0); ACB(1); ACB(2); ACB(3); ACB(4); ACB(5); ACB(6); ACB(7);
    jA += 16; jB += 16;
  }
  // interleaved 8+8
  while (jA + 8 <= endA && jB + 8 <= endB) {
    int eA0 = csr[jA + g], eA1 = csr[jA + 2 + g], eA2 = csr[jA + 4 + g], eA3 = csr[jA + 6 + g];
    int eB0 = csr[jB + g], eB1 = csr[jB + 2 + g], eB2 = csr[jB + 4 + g], eB3 = csr[jB + 6 + g];
    LDA(0); LDA(1); LDA(2); LDA(3);
    LDB(0); LDB(1); LDB(2); LDB(3);
    ACA(0); ACA(1); ACA(2); ACA(3);
    ACB(0); ACB(1); ACB(2); ACB(3);
    jA += 8; jB += 8;
  }
  // finish node A (16/8/4/pairs, index order preserved)
  for (; jA + 16 <= endA; jA += 16) {
    int eA0 = csr[jA + g],      eA1 = csr[jA + 2 + g],  eA2 = csr[jA + 4 + g],  eA3 = csr[jA + 6 + g];
    int eA4 = csr[jA + 8 + g],  eA5 = csr[jA + 10 + g], eA6 = csr[jA + 12 + g], eA7 = csr[jA + 14 + g];
    LDA(0); LDA(1); LDA(2); LDA(3); LDA(4); LDA(5); LDA(6); LDA(7);
    ACA(0); ACA(1); ACA(2); ACA(3); ACA(4); ACA(5); ACA(6); ACA(7);
  }
  if (jA + 8 <= endA) {
    int eA0 = csr[jA + g], eA1 = csr[jA + 2 + g], eA2 = csr[jA + 4 + g], eA3 = csr[jA + 6 + g];
    LDA(0); LDA(1); LDA(2); LDA(3);
    ACA(0); ACA(1); ACA(2); ACA(3);
    jA += 8;
  }
  if (jA + 4 <= endA) {
    int eA0 = csr[jA + g], eA1 = csr[jA + 2 + g];
    LDA(0); LDA(1);
    ACA(0); ACA(1);
    jA += 4;
  }
  for (int t = jA + g; t < endA; t += 2) {
    int eA0 = csr[t];
    LDA(0);
    ACA(0);
  }
  // finish node B
  for (; jB + 16 <= endB; jB += 16) {
    int eB0 = csr[jB + g],      eB1 = csr[jB + 2 + g],  eB2 = csr[jB + 4 + g],  eB3 = csr[jB + 6 + g];
    int eB4 = csr[jB + 8 + g],  eB5 = csr[jB + 10 + g], eB6 = csr[jB + 12 + g], eB7 = csr[jB + 14 + g];
    LDB(0); LDB(1); LDB(2); LDB(3); LDB(4); LDB(5); LDB(6); LDB(7);
    ACB(0); ACB(1); ACB(2); ACB(3); ACB(4); ACB(5); ACB(6); ACB(7);
  }
  if (jB + 8 <= endB) {
    int eB0 = csr[jB + g], eB1 = csr[jB + 2 + g], eB2 = csr[jB + 4 + g], eB3 = csr[jB + 6 + g];
    LDB(0); LDB(1); LDB(2); LDB(3);
    ACB(0); ACB(1); ACB(2); ACB(3);
    jB += 8;
  }
  if (jB + 4 <= endB) {
    int eB0 = csr[jB + g], eB1 = csr[jB + 2 + g];
    LDB(0); LDB(1);
    ACB(0); ACB(1);
    jB += 4;
  }
  for (int t = jB + g; t < endB; t += 2) {
    int eB0 = csr[t];
    LDB(0);
    ACB(0);
  }
  // cross-slot reduce (lanes g=0 and g=1 hold complementary partials)
  a0 += __shfl_xor(a0, 32); a1 += __shfl_xor(a1, 32);
  a2 += __shfl_xor(a2, 32); a3 += __shfl_xor(a3, 32);
  b0 += __shfl_xor(b0, 32); b1 += __shfl_xor(b1, 32);
  b2 += __shfl_xor(b2, 32); b3 += __shfl_xor(b3, 32);
  const float4 bb = *(const float4*)(bias + 4 * l);
  if (g == 0) {                                 // half-wave stores node A
    float di = dinv[nA];
    uint2 o;
    o.x = (unsigned int)f2bf(a0 * di + bb.x) | ((unsigned int)f2bf(a1 * di + bb.y) << 16);
    o.y = (unsigned int)f2bf(a2 * di + bb.z) | ((unsigned int)f2bf(a3 * di + bb.w) << 16);
    *(uint2*)(outb + (size_t)nA * 64 + 2 * l) = o;
  } else {                                      // other half stores node B
    float di = dinv[nB];
    uint2 o;
    o.x = (unsigned int)f2bf(b0 * di + bb.x) | ((unsigned int)f2bf(b1 * di + bb.y) << 16);
    o.y = (unsigned int)f2bf(b2 * di + bb.z) | ((unsigned int)f2bf(b3 * di + bb.w) << 16);
    *(uint2*)(outb + (size_t)nB * 64 + 2 * l) = o;
  }
}

// 64ch final layer: each 32-lane half handles 2 nodes interleaved (4 nodes
// per wave, 16 per block). dword per lane (2ch), single accum pair per node.

#define LDA64(k) unsigned int vA##k = H32[(size_t)eA##k * 32 + l]
#define LDB64(k) unsigned int vB##k = H32[(size_t)eB##k * 32 + l]
#define ACA64(k) { ax += bflo(vA##k); ay += bfhi(vA##k); }
#define ACB64(k) { bx += bflo(vB##k); by += bfhi(vB##k); }

__global__ __launch_bounds__(256, 4) void agg64_kernel(const unsigned int* __restrict__ H32,
    const int* __restrict__ rs, const unsigned short* __restrict__ csr,
    const float* __restrict__ dinv, const float* __restrict__ bias,
    float* __restrict__ out) {
  int l = threadIdx.x & 31;                     // dword index in row
  int nA = blockIdx.x * 16 + (threadIdx.x >> 5) * 2;
  int nB = nA + 1;
  int begA = rs[nA], endA = rs[nA + 1], endB = rs[nB + 1];
  float ax = 0.f, ay = 0.f, bx = 0.f, by = 0.f;
  int jA = begA, jB = endA;
  // interleaved 8+8 (16 loads in flight per half-wave)
  while (jA + 8 <= endA && jB + 8 <= endB) {
    int eA0 = csr[jA],     eA1 = csr[jA + 1], eA2 = csr[jA + 2], eA3 = csr[jA + 3];
    int eA4 = csr[jA + 4], eA5 = csr[jA + 5], eA6 = csr[jA + 6], eA7 = csr[jA + 7];
    int eB0 = csr[jB],     eB1 = csr[jB + 1], eB2 = csr[jB + 2], eB3 = csr[jB + 3];
    int eB4 = csr[jB + 4], eB5 = csr[jB + 5], eB6 = csr[jB + 6], eB7 = csr[jB + 7];
    LDA64(0); LDA64(1); LDA64(2); LDA64(3); LDA64(4); LDA64(5); LDA64(6); LDA64(7);
    LDB64(0); LDB64(1); LDB64(2); LDB64(3); LDB64(4); LDB64(5); LDB64(6); LDB64(7);
    ACA64(0); ACA64(1); ACA64(2); ACA64(3); ACA64(4); ACA64(5); ACA64(6); ACA64(7);
    ACB64(0); ACB64(1); ACB64(2); ACB64(3); ACB64(4); ACB64(5); ACB64(6); ACB64(7);
    jA += 8; jB += 8;
  }
  // interleaved 4+4
  while (jA + 4 <= endA && jB + 4 <= endB) {
    int eA0 = csr[jA], eA1 = csr[jA + 1], eA2 = csr[jA + 2], eA3 = csr[jA + 3];
    int eB0 = csr[jB], eB1 = csr[jB + 1], eB2 = csr[jB + 2], eB3 = csr[jB + 3];
    LDA64(0); LDA64(1); LDA64(2); LDA64(3);
    LDB64(0); LDB64(1); LDB64(2); LDB64(3);
    ACA64(0); ACA64(1); ACA64(2); ACA64(3);
    ACB64(0); ACB64(1); ACB64(2); ACB64(3);
    jA += 4; jB += 4;
  }
  // finish node A
  for (; jA + 8 <= endA; jA += 8) {
    int eA0 = csr[jA],     eA1 = csr[jA + 1], eA2 = csr[jA + 2], eA3 = csr[jA + 3];
    int eA4 = csr[jA + 4], eA5 = csr[jA + 5], eA6 = csr[jA + 6], eA7 = csr[jA + 7];
    LDA64(0); LDA64(1); LDA64(2); LDA64(3); LDA64(4); LDA64(5); LDA64(6); LDA64(7);
    ACA64(0); ACA64(1); ACA64(2); ACA64(3); ACA64(4); ACA64(5); ACA64(6); ACA64(7);
  }
  if (jA + 4 <= endA) {
    int eA0 = csr[jA], eA1 = csr[jA + 1], eA2 = csr[jA + 2], eA3 = csr[jA + 3];
    LDA64(0); LDA64(1); LDA64(2); LDA64(3);
    ACA64(0); ACA64(1); ACA64(2); ACA64(3);
    jA += 4;
  }
  for (; jA < endA; ++jA) {
    int eA0 = csr[jA];
    LDA64(0);
    ACA64(0);
  }
  // finish node B
  for (; jB + 8 <= endB; jB += 8) {
    int eB0 = csr[jB],     eB1 = csr[jB + 1], eB2 = csr[jB + 2], eB3 = csr[jB + 3];
    int eB4 = csr[jB + 4], eB5 = csr[jB + 5], eB6 = csr[jB + 6], eB7 = csr[jB + 7];
    LDB64(0); LDB64(1); LDB64(2); LDB64(3); LDB64(4); LDB64(5); LDB64(6); LDB64(7);
    ACB64(0); ACB64(1); ACB64(2); ACB64(3); ACB64(4); ACB64(5); ACB64(6); ACB64(7);
  }
  if (jB + 4 <= endB) {
    int eB0 = csr[jB], eB1 = csr[jB + 1], eB2 = csr[jB + 2], eB3 = csr[jB + 3];
    LDB64(0); LDB64(1); LDB64(2); LDB64(3);
    ACB64(0); ACB64(1); ACB64(2); ACB64(3);
    jB += 4;
  }
  for (; jB < endB; ++jB) {
    int eB0 = csr[jB];
    LDB64(0);
    ACB64(0);
  }
  int c = l * 2;
  float diA = dinv[nA], diB = dinv[nB];
  float bx0 = bias[c], bx1 = bias[c + 1];
  out[(size_t)nA * 64 + c]     = ax * diA + bx0;
  out[(size_t)nA * 64 + c + 1] = ay * diA + bx1;
  out[(size_t)nB * 64 + c]     = bx * diB + bx0;
  out[(size_t)nB * 64 + c + 1] = by * diB + bx1;
}

// ---- BN stats over bf16-packed agg output (R11 form — proven fast) -------

__global__ __launch_bounds__(256) void stats_kernel(const unsigned int* __restrict__ B32,
                                                    float* __restrict__ sums) {
  __shared__ float lsx[256], lsy[256], l2x[256], l2y[256];
  int tid = threadIdx.x;
  int d = tid & 63, grp = tid >> 6;
  float sx = 0.f, sy = 0.f, qx = 0.f, qy = 0.f;
  for (int r = blockIdx.x * 4 + grp; r < N_NODES; r += gridDim.x * 4) {
    unsigned int v = B32[(size_t)r * 64 + d];
    float x = bflo(v), y = bfhi(v);
    sx += x; sy += y; qx += x * x; qy += y * y;
  }
  lsx[tid] = sx; lsy[tid] = sy; l2x[tid] = qx; l2y[tid] = qy;
  __syncthreads();
  if (tid < 64) {
    float ax = lsx[tid] + lsx[64 + tid] + lsx[128 + tid] + lsx[192 + tid];
    float ay = lsy[tid] + lsy[64 + tid] + lsy[128 + tid] + lsy[192 + tid];
    float bx = l2x[tid] + l2x[64 + tid] + l2x[128 + tid] + l2x[192 + tid];
    float by = l2y[tid] + l2y[64 + tid] + l2y[128 + tid] + l2y[192 + tid];
    atomicAdd(&sums[2 * tid], ax);
    atomicAdd(&sums[2 * tid + 1], ay);
    atomicAdd(&sums[128 + 2 * tid], bx);
    atomicAdd(&sums[128 + 2 * tid + 1], by);
  }
}

// ---- driver --------------------------------------------------------------

extern "C" void kernel_launch(void* const* d_in, const int* in_sizes, int n_in,
                              void* d_out, int out_size, void* d_ws, size_t ws_size,
                              hipStream_t stream) {
  const float* x   = (const float*)d_in[0];
  const int*   ei  = (const int*)d_in[1];
  const float* W1  = (const float*)d_in[2];
  const float* b1  = (const float*)d_in[3];
  const float* W2  = (const float*)d_in[4];
  const float* b2  = (const float*)d_in[5];
  const float* W3  = (const float*)d_in[6];
  const float* b3  = (const float*)d_in[7];
  const float* g1  = (const float*)d_in[8];
  const float* bt1 = (const float*)d_in[9];
  const float* g2  = (const float*)d_in[10];
  const float* bt2 = (const float*)d_in[11];
  float* out = (float*)d_out;

  char* p = (char*)d_ws;
  auto carve = [&](size_t bytes) { char* r = p; p += (bytes + 255) & ~(size_t)255; return r; };
  int*   rs      = (int*)  carve((size_t)(N_NODES + 1) * 4);
  float* dinv    = (float*)carve((size_t)N_NODES * 4);
  int*   cur     = (int*)  carve((size_t)NBUCK * 4);
  unsigned int* part = (unsigned int*)carve((size_t)NBUCK * BCAP * 4);
  unsigned short* csr = (unsigned short*)carve((size_t)(TOT_E + 32) * 2);
  float* sums1   = (float*)carve(256 * 4);
  float* sums2   = (float*)carve(256 * 4);
  int*   flag    = (int*)  carve(256);
  unsigned short* Wb1 = (unsigned short*)carve(16384 * 2);
  unsigned short* Wb2 = (unsigned short*)carve(16384 * 2);
  unsigned short* Wb3 = (unsigned short*)carve(8192 * 2);
  unsigned short* Hb = (unsigned short*)carve((size_t)(N_NODES + 1) * 128 * 2);
  unsigned int*   Bb = (unsigned int*)  carve((size_t)N_NODES * 64 * 4);

  init_kernel<<<64, 256, 0, stream>>>(sums1, sums2, rs, cur, ei, flag,
                                      W1, W2, W3, Wb1, Wb2, Wb3);
  part_kernel<<<PART_BLOCKS, 1024, 0, stream>>>(ei, flag, cur, part);
  fin_kernel<<<NBUCK, 256, 0, stream>>>(part, cur, csr, rs, dinv);

  // layer 1: mm(x) -> agg -> stats
  mm_kernel<128, 0><<<(N_NODES + 63) / 64, 256, 0, stream>>>(x, sums1, g1, bt1, Wb1, dinv, Hb);
  agg128_kernel<<<N_NODES / 8, 256, 0, stream>>>((const unsigned int*)Hb, rs, csr, dinv, b1, Bb);
  stats_kernel<<<512, 256, 0, stream>>>(Bb, sums1);

  // layer 2: mm(BN1(Bb)) -> agg -> stats
  mm_kernel<128, 1><<<(N_NODES + 63) / 64, 256, 0, stream>>>(Bb, sums1, g1, bt1, Wb2, dinv, Hb);
  agg128_kernel<<<N_NODES / 8, 256, 0, stream>>>((const unsigned int*)Hb, rs, csr, dinv, b2, Bb);
  stats_kernel<<<512, 256, 0, stream>>>(Bb, sums2);

  // layer 3: mm(BN2(Bb)) -> agg -> out (fp32)
  mm_kernel<64, 1><<<(N_NODES + 63) / 64, 256, 0, stream>>>(Bb, sums2, g2, bt2, Wb3, dinv, Hb);
  agg64_kernel<<<N_NODES / 16, 256, 0, stream>>>((const unsigned int*)Hb, rs, csr, dinv, b3, out);
}